// Round 7
// baseline (195.277 us; speedup 1.0000x reference)
//
#include <hip/hip_runtime.h>

#define S_LEN   2048
#define D_MODEL 1024
#define N_HEADS 16
#define HEAD_DIM 64

typedef unsigned short u16;
typedef float  floatx4 __attribute__((ext_vector_type(4)));
typedef short  bf16x8  __attribute__((ext_vector_type(8)));

__device__ __forceinline__ u16 f2bf(float f) {
    unsigned int u = __float_as_uint(f);
    u += 0x7FFF + ((u >> 16) & 1);      // RNE
    return (u16)(u >> 16);
}
__device__ __forceinline__ unsigned pack2bf(float a, float b) {
    return (unsigned)f2bf(a) | ((unsigned)f2bf(b) << 16);
}

// global -> LDS direct copy, 16B/lane. LDS dest = wave-uniform base + lane*16.
__device__ __forceinline__ void gload_lds16(const void* g, void* l) {
    __builtin_amdgcn_global_load_lds(
        reinterpret_cast<const __attribute__((address_space(1))) unsigned int*>(
            reinterpret_cast<uintptr_t>(g)),
        reinterpret_cast<__attribute__((address_space(3))) unsigned int*>(
            reinterpret_cast<uintptr_t>(l)),
        16, 0, 0);
}

// ---------------------------------------------------------------------------
// Single fused fp32 -> bf16 cast for hs + 4 weights (dst regions contiguous).
// ---------------------------------------------------------------------------
__global__ __launch_bounds__(256) void cast_all(const float* __restrict__ hs,
                                                const float* __restrict__ w0,
                                                const float* __restrict__ w1,
                                                const float* __restrict__ w2,
                                                const float* __restrict__ w3,
                                                u16* __restrict__ dst) {
    const size_t NHS = (size_t)2 * S_LEN * D_MODEL;   // 4M
    const size_t e0 = (size_t)blockIdx.x * 2048;      // block-uniform range
    const float* src;
    size_t base;
    if (e0 < NHS)                 { src = hs; base = 0; }
    else {
        const int wi = (int)((e0 - NHS) >> 20);       // 1M-element weights
        src = wi == 0 ? w0 : wi == 1 ? w1 : wi == 2 ? w2 : w3;
        base = NHS + ((size_t)wi << 20);
    }
    const size_t i = e0 + (size_t)threadIdx.x * 8;
    const float4 a = *(const float4*)(src + (i - base));
    const float4 b = *(const float4*)(src + (i - base) + 4);
    uint4 o;
    o.x = pack2bf(a.x, a.y); o.y = pack2bf(a.z, a.w);
    o.z = pack2bf(b.x, b.y); o.w = pack2bf(b.z, b.w);
    *(uint4*)(dst + i) = o;
}

// ---------------------------------------------------------------------------
// Per-head V transpose (head (b,h) is a CONTIGUOUS (2048 s, 64 d) chunk under
// the module's flat view). Vt[bh][d][s]. Coalesced both sides via LDS.
// ---------------------------------------------------------------------------
__global__ __launch_bounds__(256) void vtrans(const u16* __restrict__ Vf,
                                              u16* __restrict__ Vt) {
    __shared__ unsigned T[64 * 133];
    const int bh = blockIdx.y;            // 0..31
    const int sBase = blockIdx.x * 128;
    const u16* src = Vf + (size_t)bh * (S_LEN * HEAD_DIM) + (size_t)sBase * HEAD_DIM;
    u16* dst = Vt + (size_t)bh * (S_LEN * HEAD_DIM) + sBase;
    const int tid = threadIdx.x;

#pragma unroll
    for (int it = 0; it < 4; ++it) {
        const int idx = it * 256 + tid;
        const int row = idx >> 3, ch = idx & 7;
        const float4 v4 = *(const float4*)(src + row * 64 + ch * 8);
        const u16* vs = (const u16*)&v4;
#pragma unroll
        for (int j = 0; j < 8; ++j) T[(ch * 8 + j) * 133 + row] = vs[j];
    }
    __syncthreads();
#pragma unroll
    for (int it = 0; it < 4; ++it) {
        const int idx = it * 256 + tid;
        const int d = idx >> 4, sc = idx & 15;
        union { u16 u[8]; float4 f; } tmp;
#pragma unroll
        for (int j = 0; j < 8; ++j) tmp.u[j] = (u16)T[d * 133 + sc * 8 + j];
        *(float4*)(dst + (size_t)d * S_LEN + sc * 8) = tmp.f;
    }
}

// ---------------------------------------------------------------------------
// Fused QKV GEMM (m97 structure, 128x128, BK=32, global_load_lds, XOR swizzle).
// 1D grid 768, XCD-by-m-tile mapping (blk%8 == mtile%8) for A-tile L2 locality.
// Q pre-scaled by log2e/64. Standard (row,col) outputs.
// ---------------------------------------------------------------------------
__global__ __launch_bounds__(256) void gemm_qkv(const u16* __restrict__ A,
                                                const u16* __restrict__ Wq,
                                                const u16* __restrict__ Wk,
                                                const u16* __restrict__ Wv,
                                                u16* __restrict__ Qo,
                                                u16* __restrict__ Ko,
                                                u16* __restrict__ Vfo) {
    __shared__ u16 As[8 * 512];
    __shared__ u16 Ws[8 * 512];

    const int blk = blockIdx.x;                            // 0..767
    const int y   = (blk & 7) | (((blk >> 3) & 3) << 3);   // m-tile, XCD = y%8
    const int x   = blk >> 5;                              // 0..23
    const int which = x >> 3;
    const int nBase = (x & 7) * 128;
    const int mBase = y * 128;
    const u16* W = which == 0 ? Wq : which == 1 ? Wk : Wv;

    const int tid = threadIdx.x, lane = tid & 63, wv = tid >> 6;
    const int l15 = lane & 15, quad = lane >> 4;
    const int wm = wv & 1, wn = wv >> 1;
    const int srow = lane >> 2;                        // 0..15
    const int gch  = (lane & 3) ^ ((lane >> 3) & 3);   // swizzled src chunk
    const int swz  = (l15 >> 1) & 3;                   // read-side swizzle

    floatx4 acc[4][4];
#pragma unroll
    for (int i = 0; i < 4; ++i)
#pragma unroll
        for (int j = 0; j < 4; ++j) acc[i][j] = (floatx4)(0.0f);

    for (int k0 = 0; k0 < D_MODEL; k0 += 32) {
        __syncthreads();
#pragma unroll
        for (int t = 0; t < 2; ++t) {
            const int ci = wv * 2 + t;
            gload_lds16(A + (size_t)(mBase + ci * 16 + srow) * D_MODEL + k0 + gch * 8,
                        &As[ci * 512]);
            gload_lds16(W + (size_t)(nBase + ci * 16 + srow) * D_MODEL + k0 + gch * 8,
                        &Ws[ci * 512]);
        }
        __syncthreads();

        bf16x8 af[4], bfr[4];
#pragma unroll
        for (int mt = 0; mt < 4; ++mt)
            af[mt] = *(const bf16x8*)&As[(wm * 64 + mt * 16 + l15) * 32 + (quad ^ swz) * 8];
#pragma unroll
        for (int nt = 0; nt < 4; ++nt)
            bfr[nt] = *(const bf16x8*)&Ws[(wn * 64 + nt * 16 + l15) * 32 + (quad ^ swz) * 8];
#pragma unroll
        for (int mt = 0; mt < 4; ++mt)
#pragma unroll
            for (int nt = 0; nt < 4; ++nt)
                acc[mt][nt] = __builtin_amdgcn_mfma_f32_16x16x32_bf16(af[mt], bfr[nt], acc[mt][nt], 0, 0, 0);
    }

    u16* O = which == 0 ? Qo : (which == 1 ? Ko : Vfo);
    const float scale = which == 0 ? (1.44269504088896f / 64.0f) : 1.0f;
#pragma unroll
    for (int mt = 0; mt < 4; ++mt)
#pragma unroll
        for (int nt = 0; nt < 4; ++nt) {
            const int col = nBase + wn * 64 + nt * 16 + l15;
#pragma unroll
            for (int r = 0; r < 4; ++r) {
                const int row = mBase + wm * 64 + mt * 16 + quad * 4 + r;
                O[(size_t)row * D_MODEL + col] = f2bf(acc[mt][nt][r] * scale);
            }
        }
}

// ---------------------------------------------------------------------------
// O-projection GEMM: 64x128 tile (512 blocks -> 2/CU), BK=32, fp32 out + bias.
// ---------------------------------------------------------------------------
__global__ __launch_bounds__(256) void gemm_out(const u16* __restrict__ A,
                                                const u16* __restrict__ W,
                                                const float* __restrict__ bias,
                                                float* __restrict__ C) {
    __shared__ u16 As[4 * 512];
    __shared__ u16 Ws[8 * 512];

    const int nBase = blockIdx.x * 128;
    const int mBase = blockIdx.y * 64;
    const int tid = threadIdx.x, lane = tid & 63, wv = tid >> 6;
    const int l15 = lane & 15, quad = lane >> 4;
    const int wm = wv & 1, wn = wv >> 1;
    const int srow = lane >> 2;
    const int gch  = (lane & 3) ^ ((lane >> 3) & 3);
    const int swz  = (l15 >> 1) & 3;

    floatx4 acc[2][4];
#pragma unroll
    for (int i = 0; i < 2; ++i)
#pragma unroll
        for (int j = 0; j < 4; ++j) acc[i][j] = (floatx4)(0.0f);

    for (int k0 = 0; k0 < D_MODEL; k0 += 32) {
        __syncthreads();
        gload_lds16(A + (size_t)(mBase + wv * 16 + srow) * D_MODEL + k0 + gch * 8,
                    &As[wv * 512]);
#pragma unroll
        for (int t = 0; t < 2; ++t) {
            const int ci = wv * 2 + t;
            gload_lds16(W + (size_t)(nBase + ci * 16 + srow) * D_MODEL + k0 + gch * 8,
                        &Ws[ci * 512]);
        }
        __syncthreads();

        bf16x8 af[2], bfr[4];
#pragma unroll
        for (int mt = 0; mt < 2; ++mt)
            af[mt] = *(const bf16x8*)&As[(wm * 32 + mt * 16 + l15) * 32 + (quad ^ swz) * 8];
#pragma unroll
        for (int nt = 0; nt < 4; ++nt)
            bfr[nt] = *(const bf16x8*)&Ws[(wn * 64 + nt * 16 + l15) * 32 + (quad ^ swz) * 8];
#pragma unroll
        for (int mt = 0; mt < 2; ++mt)
#pragma unroll
            for (int nt = 0; nt < 4; ++nt)
                acc[mt][nt] = __builtin_amdgcn_mfma_f32_16x16x32_bf16(af[mt], bfr[nt], acc[mt][nt], 0, 0, 0);
    }

#pragma unroll
    for (int mt = 0; mt < 2; ++mt)
#pragma unroll
        for (int nt = 0; nt < 4; ++nt) {
            const int col = nBase + wn * 64 + nt * 16 + l15;
            const float bv = bias[col];
#pragma unroll
            for (int r = 0; r < 4; ++r) {
                const int row = mBase + wm * 32 + mt * 16 + quad * 4 + r;
                C[(size_t)row * D_MODEL + col] = acc[mt][nt][r] + bv;
            }
        }
}

// ---------------------------------------------------------------------------
// Per-(64q subset, 64k tile) work: QK^T (transposed trick), exp2, pack to Ps,
// PV accumulate. Wave-private Ps region -> in-wave DS ordering, no barrier.
// ---------------------------------------------------------------------------
__device__ __forceinline__ void attn_sub(const u16* __restrict__ Ks,
                                         const u16* __restrict__ Vs,
                                         u16* __restrict__ Psw,
                                         const bf16x8 qa[2],
                                         floatx4 o[4], float& lp,
                                         bool diag, int l15, int quad, int wv, int swz) {
    // S^T = K.Q^T : A = K tile (64 keys), B = 16 queries
    floatx4 s[4];
#pragma unroll
    for (int mt = 0; mt < 4; ++mt) {
        s[mt] = (floatx4)(0.0f);
#pragma unroll
        for (int ks = 0; ks < 2; ++ks) {
            const bf16x8 kb = *(const bf16x8*)&Ks[(mt * 16 + l15) * 64 + ((ks * 4 + quad) ^ swz) * 8];
            s[mt] = __builtin_amdgcn_mfma_f32_16x16x32_bf16(kb, qa[ks], s[mt], 0, 0, 0);
        }
    }
    // p = exp2(s); lane holds P[query=l15][key=mt*16+quad*4+r]
#pragma unroll
    for (int mt = 0; mt < 4; ++mt) {
        float p[4];
#pragma unroll
        for (int r = 0; r < 4; ++r) {
            float pv = exp2f(s[mt][r]);
            if (diag && (mt * 16 + quad * 4 + r > wv * 16 + l15)) pv = 0.0f;
            p[r] = pv;
            lp += pv;
        }
        uint2 w;
        w.x = __builtin_amdgcn_perm(__float_as_uint(p[1]), __float_as_uint(p[0]), 0x07060302);
        w.y = __builtin_amdgcn_perm(__float_as_uint(p[3]), __float_as_uint(p[2]), 0x07060302);
        *(uint2*)&Psw[l15 * 72 + mt * 16 + quad * 4] = w;
    }
    // O += P.V
    bf16x8 pa[2];
#pragma unroll
    for (int ks = 0; ks < 2; ++ks)
        pa[ks] = *(const bf16x8*)&Psw[l15 * 72 + ks * 32 + quad * 8];
#pragma unroll
    for (int nt = 0; nt < 4; ++nt)
#pragma unroll
        for (int ks = 0; ks < 2; ++ks) {
            const bf16x8 vb = *(const bf16x8*)&Vs[(nt * 16 + l15) * 64 + ((ks * 4 + quad) ^ swz) * 8];
            o[nt] = __builtin_amdgcn_mfma_f32_16x16x32_bf16(pa[ks], vb, o[nt], 0, 0, 0);
        }
}

// ---------------------------------------------------------------------------
// MFMA flash attention v5: 128-query blocks (32 q/wave in 2 subsets), grid 512.
//  - K/V LDS reads amortized over 2x queries (LDS pipe was the round-6 limit).
//  - sub0 skipped entirely on its fully-masked last tile -> zero waste.
//  - Longest-first (qb = 15 - flat>>5), XCD pinning (g = flat&31, 32 % 8 == 0).
// ---------------------------------------------------------------------------
__global__ __launch_bounds__(256) void attn5(const u16* __restrict__ Q,
                                             const u16* __restrict__ K,
                                             const u16* __restrict__ Vt,
                                             u16* __restrict__ Ctx) {
    __shared__ u16 Ks[8 * 512];
    __shared__ u16 Vs[8 * 512];
    __shared__ u16 Ps[4][16 * 72];

    const int flat = blockIdx.x;          // 0..511
    const int g    = flat & 31;           // (b*16+h); XCD = g%8
    const int qb   = 15 - (flat >> 5);    // longest blocks first
    const int h = g & 15, b = g >> 4;

    const int tid = threadIdx.x, lane = tid & 63, wv = tid >> 6;
    const int l15 = lane & 15, quad = lane >> 4;

    const size_t headOff = ((size_t)b * N_HEADS + h) * S_LEN * HEAD_DIM;
    const u16* Qh = Q + headOff;
    const u16* Kh = K + headOff;
    const u16* Vh = Vt + headOff;         // d-major: [64][2048]
    u16* Cb = Ctx + (size_t)b * S_LEN * D_MODEL + (size_t)h * HEAD_DIM;

    const int srow = lane >> 3;           // 0..7 row within 8-row chunk
    const int gch  = (lane & 7) ^ srow;   // swizzled source chunk
    const int swz  = l15 & 7;             // read-side swizzle

    const int qBase = qb * 128;

    bf16x8 qa[2][2];                      // [subset][ks]
#pragma unroll
    for (int sub = 0; sub < 2; ++sub)
#pragma unroll
        for (int ks = 0; ks < 2; ++ks)
            qa[sub][ks] = *(const bf16x8*)(Qh + (size_t)(qBase + sub * 64 + wv * 16 + l15) * 64
                                           + ks * 32 + quad * 8);

    floatx4 oA[4], oB[4];
#pragma unroll
    for (int nt = 0; nt < 4; ++nt) { oA[nt] = (floatx4)(0.0f); oB[nt] = (floatx4)(0.0f); }
    float lpA = 0.0f, lpB = 0.0f;

    const int kmax = 2 * qb + 1;
    for (int kt = 0; kt <= kmax; ++kt) {
        const int kBase = kt * 64;
        __syncthreads();                  // previous iteration done reading LDS
#pragma unroll
        for (int t = 0; t < 2; ++t) {
            const int ci = wv * 2 + t;
            gload_lds16(Kh + (size_t)(kBase + ci * 8 + srow) * 64 + gch * 8, &Ks[ci * 512]);
            gload_lds16(Vh + (size_t)(ci * 8 + srow) * S_LEN + kBase + gch * 8, &Vs[ci * 512]);
        }
        __syncthreads();                  // vmcnt(0) drains at barrier

        if (kt <= 2 * qb)                 // sub0 fully masked on the last tile
            attn_sub(Ks, Vs, Ps[wv], qa[0], oA, lpA, kt == 2 * qb, l15, quad, wv, swz);
        attn_sub(Ks, Vs, Ps[wv], qa[1], oB, lpB, kt == kmax, l15, quad, wv, swz);
    }

    // row sums (query = l15): lanes with same l15 hold partials -> 2 shfls
    lpA += __shfl_xor(lpA, 16); lpA += __shfl_xor(lpA, 32);
    lpB += __shfl_xor(lpB, 16); lpB += __shfl_xor(lpB, 32);

#pragma unroll
    for (int r = 0; r < 4; ++r) {
        const float invA = 1.0f / __shfl(lpA, quad * 4 + r);   // lane l15 = quad*4+r
        const float invB = 1.0f / __shfl(lpB, quad * 4 + r);
        const int rowA = qBase + wv * 16 + quad * 4 + r;
#pragma unroll
        for (int nt = 0; nt < 4; ++nt) {
            Cb[(size_t)rowA * D_MODEL + nt * 16 + l15]        = f2bf(oA[nt][r] * invA);
            Cb[(size_t)(rowA + 64) * D_MODEL + nt * 16 + l15] = f2bf(oB[nt][r] * invB);
        }
    }
}

// ---------------------------------------------------------------------------
extern "C" void kernel_launch(void* const* d_in, const int* in_sizes, int n_in,
                              void* d_out, int out_size, void* d_ws, size_t ws_size,
                              hipStream_t stream) {
    const float* hs = (const float*)d_in[0];
    const float* Wq = (const float*)d_in[1];
    const float* Wk = (const float*)d_in[2];
    const float* Wv = (const float*)d_in[3];
    const float* Wo = (const float*)d_in[4];
    const float* bo = (const float*)d_in[5];
    float* out = (float*)d_out;

    const size_t NHS = (size_t)2 * S_LEN * D_MODEL;  // 4M elements
    const size_t NW  = (size_t)D_MODEL * D_MODEL;    // 1M elements

    u16* hsb = (u16*)d_ws;        // 4M
    u16* Wb  = hsb + NHS;         // 4 x 1M (Wq,Wk,Wv,Wo) — contiguous with hsb
    u16* Qb  = Wb + 4 * NW;       // 4M
    u16* Kb  = Qb + NHS;          // 4M
    u16* Vfb = Kb + NHS;          // 4M (standard projection layout)
    u16* Vtb = Vfb + NHS;         // 4M (per-head transposed [d][s])
    u16* Cxb = Vtb + NHS;         // 4M

    cast_all<<<4096, 256, 0, stream>>>(hs, Wq, Wk, Wv, Wo, hsb);

    gemm_qkv<<<768, 256, 0, stream>>>(hsb, Wb, Wb + NW, Wb + 2 * NW,
                                      Qb, Kb, Vfb);

    vtrans<<<dim3(16, 32), 256, 0, stream>>>(Vfb, Vtb);

    attn5<<<512, 256, 0, stream>>>(Qb, Kb, Vtb, Cxb);

    gemm_out<<<dim3(8, 64), 256, 0, stream>>>(Cxb, Wb + 3 * NW, bo, out);
}

// Round 8
// 172.704 us; speedup vs baseline: 1.1307x; 1.1307x over previous
//
#include <hip/hip_runtime.h>

#define S_LEN   2048
#define D_MODEL 1024
#define N_HEADS 16
#define HEAD_DIM 64

typedef unsigned short u16;
typedef float  floatx4 __attribute__((ext_vector_type(4)));
typedef short  bf16x8  __attribute__((ext_vector_type(8)));
typedef short  bf16x4  __attribute__((ext_vector_type(4)));

__device__ __forceinline__ u16 f2bf(float f) {
    unsigned int u = __float_as_uint(f);
    u += 0x7FFF + ((u >> 16) & 1);      // RNE
    return (u16)(u >> 16);
}
__device__ __forceinline__ unsigned pack2bf(float a, float b) {
    return (unsigned)f2bf(a) | ((unsigned)f2bf(b) << 16);
}

// global -> LDS direct copy, 16B/lane. LDS dest = wave-uniform base + lane*16.
__device__ __forceinline__ void gload_lds16(const void* g, void* l) {
    __builtin_amdgcn_global_load_lds(
        reinterpret_cast<const __attribute__((address_space(1))) unsigned int*>(
            reinterpret_cast<uintptr_t>(g)),
        reinterpret_cast<__attribute__((address_space(3))) unsigned int*>(
            reinterpret_cast<uintptr_t>(l)),
        16, 0, 0);
}

// ---------------------------------------------------------------------------
// Single fused fp32 -> bf16 cast for hs + 4 weights (dst regions contiguous).
// ---------------------------------------------------------------------------
__global__ __launch_bounds__(256) void cast_all(const float* __restrict__ hs,
                                                const float* __restrict__ w0,
                                                const float* __restrict__ w1,
                                                const float* __restrict__ w2,
                                                const float* __restrict__ w3,
                                                u16* __restrict__ dst) {
    const size_t NHS = (size_t)2 * S_LEN * D_MODEL;   // 4M
    const size_t e0 = (size_t)blockIdx.x * 2048;      // block-uniform range
    const float* src;
    size_t base;
    if (e0 < NHS)                 { src = hs; base = 0; }
    else {
        const int wi = (int)((e0 - NHS) >> 20);       // 1M-element weights
        src = wi == 0 ? w0 : wi == 1 ? w1 : wi == 2 ? w2 : w3;
        base = NHS + ((size_t)wi << 20);
    }
    const size_t i = e0 + (size_t)threadIdx.x * 8;
    const float4 a = *(const float4*)(src + (i - base));
    const float4 b = *(const float4*)(src + (i - base) + 4);
    uint4 o;
    o.x = pack2bf(a.x, a.y); o.y = pack2bf(a.z, a.w);
    o.z = pack2bf(b.x, b.y); o.w = pack2bf(b.z, b.w);
    *(uint4*)(dst + i) = o;
}

// ---------------------------------------------------------------------------
// Per-head V transpose (head (b,h) is a CONTIGUOUS (2048 s, 64 d) chunk under
// the module's flat view). Vt[bh][d][s]. Coalesced both sides via LDS.
// ---------------------------------------------------------------------------
__global__ __launch_bounds__(256) void vtrans(const u16* __restrict__ Vf,
                                              u16* __restrict__ Vt) {
    __shared__ unsigned T[64 * 133];
    const int bh = blockIdx.y;            // 0..31
    const int sBase = blockIdx.x * 128;
    const u16* src = Vf + (size_t)bh * (S_LEN * HEAD_DIM) + (size_t)sBase * HEAD_DIM;
    u16* dst = Vt + (size_t)bh * (S_LEN * HEAD_DIM) + sBase;
    const int tid = threadIdx.x;

#pragma unroll
    for (int it = 0; it < 4; ++it) {
        const int idx = it * 256 + tid;
        const int row = idx >> 3, ch = idx & 7;
        const float4 v4 = *(const float4*)(src + row * 64 + ch * 8);
        const u16* vs = (const u16*)&v4;
#pragma unroll
        for (int j = 0; j < 8; ++j) T[(ch * 8 + j) * 133 + row] = vs[j];
    }
    __syncthreads();
#pragma unroll
    for (int it = 0; it < 4; ++it) {
        const int idx = it * 256 + tid;
        const int d = idx >> 4, sc = idx & 15;
        union { u16 u[8]; float4 f; } tmp;
#pragma unroll
        for (int j = 0; j < 8; ++j) tmp.u[j] = (u16)T[d * 133 + sc * 8 + j];
        *(float4*)(dst + (size_t)d * S_LEN + sc * 8) = tmp.f;
    }
}

// ---------------------------------------------------------------------------
// Fused QKV GEMM (m97 structure, 128x128, BK=32, global_load_lds, XOR swizzle).
// 1D grid 768, XCD-by-m-tile mapping (blk%8 == mtile%8) for A-tile L2 locality.
// Q pre-scaled by log2e/64. Standard (row,col) outputs.
// ---------------------------------------------------------------------------
__global__ __launch_bounds__(256) void gemm_qkv(const u16* __restrict__ A,
                                                const u16* __restrict__ Wq,
                                                const u16* __restrict__ Wk,
                                                const u16* __restrict__ Wv,
                                                u16* __restrict__ Qo,
                                                u16* __restrict__ Ko,
                                                u16* __restrict__ Vfo) {
    __shared__ u16 As[8 * 512];
    __shared__ u16 Ws[8 * 512];

    const int blk = blockIdx.x;                            // 0..767
    const int y   = (blk & 7) | (((blk >> 3) & 3) << 3);   // m-tile, XCD = y%8
    const int x   = blk >> 5;                              // 0..23
    const int which = x >> 3;
    const int nBase = (x & 7) * 128;
    const int mBase = y * 128;
    const u16* W = which == 0 ? Wq : which == 1 ? Wk : Wv;

    const int tid = threadIdx.x, lane = tid & 63, wv = tid >> 6;
    const int l15 = lane & 15, quad = lane >> 4;
    const int wm = wv & 1, wn = wv >> 1;
    const int srow = lane >> 2;                        // 0..15
    const int gch  = (lane & 3) ^ ((lane >> 3) & 3);   // swizzled src chunk
    const int swz  = (l15 >> 1) & 3;                   // read-side swizzle

    floatx4 acc[4][4];
#pragma unroll
    for (int i = 0; i < 4; ++i)
#pragma unroll
        for (int j = 0; j < 4; ++j) acc[i][j] = (floatx4)(0.0f);

    for (int k0 = 0; k0 < D_MODEL; k0 += 32) {
        __syncthreads();
#pragma unroll
        for (int t = 0; t < 2; ++t) {
            const int ci = wv * 2 + t;
            gload_lds16(A + (size_t)(mBase + ci * 16 + srow) * D_MODEL + k0 + gch * 8,
                        &As[ci * 512]);
            gload_lds16(W + (size_t)(nBase + ci * 16 + srow) * D_MODEL + k0 + gch * 8,
                        &Ws[ci * 512]);
        }
        __syncthreads();

        bf16x8 af[4], bfr[4];
#pragma unroll
        for (int mt = 0; mt < 4; ++mt)
            af[mt] = *(const bf16x8*)&As[(wm * 64 + mt * 16 + l15) * 32 + (quad ^ swz) * 8];
#pragma unroll
        for (int nt = 0; nt < 4; ++nt)
            bfr[nt] = *(const bf16x8*)&Ws[(wn * 64 + nt * 16 + l15) * 32 + (quad ^ swz) * 8];
#pragma unroll
        for (int mt = 0; mt < 4; ++mt)
#pragma unroll
            for (int nt = 0; nt < 4; ++nt)
                acc[mt][nt] = __builtin_amdgcn_mfma_f32_16x16x32_bf16(af[mt], bfr[nt], acc[mt][nt], 0, 0, 0);
    }

    u16* O = which == 0 ? Qo : (which == 1 ? Ko : Vfo);
    const float scale = which == 0 ? (1.44269504088896f / 64.0f) : 1.0f;
#pragma unroll
    for (int mt = 0; mt < 4; ++mt)
#pragma unroll
        for (int nt = 0; nt < 4; ++nt) {
            const int col = nBase + wn * 64 + nt * 16 + l15;
#pragma unroll
            for (int r = 0; r < 4; ++r) {
                const int row = mBase + wm * 64 + mt * 16 + quad * 4 + r;
                O[(size_t)row * D_MODEL + col] = f2bf(acc[mt][nt][r] * scale);
            }
        }
}

// ---------------------------------------------------------------------------
// O-projection GEMM: 64x128 tile (512 blocks -> 2/CU), BK=32, fp32 out + bias.
// ---------------------------------------------------------------------------
__global__ __launch_bounds__(256) void gemm_out(const u16* __restrict__ A,
                                                const u16* __restrict__ W,
                                                const float* __restrict__ bias,
                                                float* __restrict__ C) {
    __shared__ u16 As[4 * 512];
    __shared__ u16 Ws[8 * 512];

    const int nBase = blockIdx.x * 128;
    const int mBase = blockIdx.y * 64;
    const int tid = threadIdx.x, lane = tid & 63, wv = tid >> 6;
    const int l15 = lane & 15, quad = lane >> 4;
    const int wm = wv & 1, wn = wv >> 1;
    const int srow = lane >> 2;
    const int gch  = (lane & 3) ^ ((lane >> 3) & 3);
    const int swz  = (l15 >> 1) & 3;

    floatx4 acc[2][4];
#pragma unroll
    for (int i = 0; i < 2; ++i)
#pragma unroll
        for (int j = 0; j < 4; ++j) acc[i][j] = (floatx4)(0.0f);

    for (int k0 = 0; k0 < D_MODEL; k0 += 32) {
        __syncthreads();
        gload_lds16(A + (size_t)(mBase + wv * 16 + srow) * D_MODEL + k0 + gch * 8,
                    &As[wv * 512]);
#pragma unroll
        for (int t = 0; t < 2; ++t) {
            const int ci = wv * 2 + t;
            gload_lds16(W + (size_t)(nBase + ci * 16 + srow) * D_MODEL + k0 + gch * 8,
                        &Ws[ci * 512]);
        }
        __syncthreads();

        bf16x8 af[2], bfr[4];
#pragma unroll
        for (int mt = 0; mt < 2; ++mt)
            af[mt] = *(const bf16x8*)&As[(wm * 32 + mt * 16 + l15) * 32 + (quad ^ swz) * 8];
#pragma unroll
        for (int nt = 0; nt < 4; ++nt)
            bfr[nt] = *(const bf16x8*)&Ws[(wn * 64 + nt * 16 + l15) * 32 + (quad ^ swz) * 8];
#pragma unroll
        for (int mt = 0; mt < 2; ++mt)
#pragma unroll
            for (int nt = 0; nt < 4; ++nt)
                acc[mt][nt] = __builtin_amdgcn_mfma_f32_16x16x32_bf16(af[mt], bfr[nt], acc[mt][nt], 0, 0, 0);
    }

#pragma unroll
    for (int mt = 0; mt < 2; ++mt)
#pragma unroll
        for (int nt = 0; nt < 4; ++nt) {
            const int col = nBase + wn * 64 + nt * 16 + l15;
            const float bv = bias[col];
#pragma unroll
            for (int r = 0; r < 4; ++r) {
                const int row = mBase + wm * 32 + mt * 16 + quad * 4 + r;
                C[(size_t)row * D_MODEL + col] = acc[mt][nt][r] + bv;
            }
        }
}

// ---------------------------------------------------------------------------
// MFMA flash attention v6: key-split across waves.
// Block = 64 queries (1024 blocks, longest-first, XCD-pinned). Within a tile,
// wave w owns keys [w*16, w*16+16) and computes S for ALL 64 queries:
//   S^T slice = MFMA16x16x32(A = K-slice[16key][64d] from LDS,
//                            B = Q^T[64d][16q] from registers)   x 4 qg x 2 ks
// Output lane layout (l15=q, quad*4+r=key_local) IS the A-operand layout of
// mfma_f32_16x16x16_bf16 -> P feeds PV directly from registers (NO LDS trip):
//   O_partial[q][d] += MFMA16x16x16(A = P-slice, B = V[16key][16d] from Vs)
// Per wave-tile LDS: 2 b128 (K) + 4 b64 (V) = 4 KB (was 18 KB).
// End of block: tree-reduce the 4 waves' partial O through LDS (once).
// ---------------------------------------------------------------------------
__global__ __launch_bounds__(256, 3) void attn6(const u16* __restrict__ Q,
                                                const u16* __restrict__ K,
                                                const u16* __restrict__ Vt,
                                                u16* __restrict__ Ctx) {
    __shared__ u16 Ks[4096];              // K tile [key][d], swizzled chunks
    __shared__ u16 Vs[4096];              // Vt tile [d][key], swizzled chunks
    __shared__ float RedA[64 * 68];       // O reduction buffers (pad 68)
    __shared__ float RedB[64 * 68];
    __shared__ float lpbuf[4 * 64];

    const int flat = blockIdx.x;          // 0..1023
    const int g    = flat & 31;           // (b*16+h); XCD = g%8 (32 % 8 == 0)
    const int qt   = 31 - (flat >> 5);    // longest blocks first
    const int h = g & 15, b = g >> 4;

    const int tid = threadIdx.x, lane = tid & 63, wv = tid >> 6;
    const int l15 = lane & 15, quad = lane >> 4;

    const size_t headOff = ((size_t)b * N_HEADS + h) * S_LEN * HEAD_DIM;
    const u16* Qh = Q + headOff;
    const u16* Kh = K + headOff;
    const u16* Vh = Vt + headOff;         // d-major: [64][2048]
    u16* Cb = Ctx + (size_t)b * S_LEN * D_MODEL + (size_t)h * HEAD_DIM;

    const int srow = lane >> 3;           // staging: row within 8-row chunk
    const int gch  = (lane & 7) ^ srow;   // swizzled source chunk
    const int swz  = l15 & 7;             // read-side swizzle (row&7 == l15&7)

    const int qBase = qt * 64;

    // Q rows for all 64 queries: qb[qg][ks] = Q[qBase+qg*16+l15][ks*32+quad*8..]
    bf16x8 qb[4][2];
#pragma unroll
    for (int qg = 0; qg < 4; ++qg)
#pragma unroll
        for (int ks = 0; ks < 2; ++ks)
            qb[qg][ks] = *(const bf16x8*)(Qh + (size_t)(qBase + qg * 16 + l15) * 64
                                          + ks * 32 + quad * 8);

    floatx4 o[4][4];                      // O_partial[qg][dg], lane: q=quad*4+r, d=l15
#pragma unroll
    for (int qg = 0; qg < 4; ++qg)
#pragma unroll
        for (int dg = 0; dg < 4; ++dg) o[qg][dg] = (floatx4)(0.0f);
    float lp[4] = {0.0f, 0.0f, 0.0f, 0.0f};

    for (int kt = 0; kt <= qt; ++kt) {
        const int kBase = kt * 64;
        __syncthreads();                  // previous iteration done reading LDS
#pragma unroll
        for (int t = 0; t < 2; ++t) {
            const int ci = wv * 2 + t;
            gload_lds16(Kh + (size_t)(kBase + ci * 8 + srow) * 64 + gch * 8, &Ks[ci * 512]);
            gload_lds16(Vh + (size_t)(ci * 8 + srow) * S_LEN + kBase + gch * 8, &Vs[ci * 512]);
        }
        __syncthreads();                  // vmcnt(0) drains at barrier

        // K A-frags for this wave's 16 keys (rows wv*16+l15)
        bf16x8 ka[2];
#pragma unroll
        for (int ks = 0; ks < 2; ++ks)
            ka[ks] = *(const bf16x8*)&Ks[(wv * 16 + l15) * 64 + ((ks * 4 + quad) ^ swz) * 8];

        // V B-frags: V[key=wv*16+quad*4+j][d=dg*16+l15] from Vs[d][key]
        bf16x4 vb[4];
#pragma unroll
        for (int dg = 0; dg < 4; ++dg)
            vb[dg] = *(const bf16x4*)&Vs[(dg * 16 + l15) * 64
                                         + (((wv * 2 + (quad >> 1)) ^ swz) * 8) + (quad & 1) * 4];

        // S^T slices: s[qg][r] = S[key=wv*16+quad*4+r][q=qg*16+l15]
        floatx4 s[4];
#pragma unroll
        for (int qg = 0; qg < 4; ++qg) {
            s[qg] = (floatx4)(0.0f);
#pragma unroll
            for (int ks = 0; ks < 2; ++ks)
                s[qg] = __builtin_amdgcn_mfma_f32_16x16x32_bf16(ka[ks], qb[qg][ks], s[qg], 0, 0, 0);
        }

        const bool diag = (kt == qt);
#pragma unroll
        for (int qg = 0; qg < 4; ++qg) {
            if (diag && qg < wv) continue;          // fully masked (wave-uniform)
            float p[4];
#pragma unroll
            for (int r = 0; r < 4; ++r) {
                float pv = __builtin_amdgcn_exp2f(s[qg][r]);
                if (diag && qg == wv && (quad * 4 + r > l15)) pv = 0.0f;
                p[r] = pv;
                lp[qg] += pv;
            }
            union { uint2 u; bf16x4 v; } pk;
            pk.u.x = __builtin_amdgcn_perm(__float_as_uint(p[1]), __float_as_uint(p[0]), 0x07060302);
            pk.u.y = __builtin_amdgcn_perm(__float_as_uint(p[3]), __float_as_uint(p[2]), 0x07060302);
#pragma unroll
            for (int dg = 0; dg < 4; ++dg)
                o[qg][dg] = __builtin_amdgcn_mfma_f32_16x16x16bf16_1k(pk.v, vb[dg], o[qg][dg], 0, 0, 0);
        }
    }

    // lp: sum this wave's 16-key slice across quads -> lpbuf[w][q]
#pragma unroll
    for (int qg = 0; qg < 4; ++qg) {
        lp[qg] += __shfl_xor(lp[qg], 16);
        lp[qg] += __shfl_xor(lp[qg], 32);
    }
    lpbuf[wv * 64 + quad * 16 + l15] = lp[quad];

    // O tree reduction across waves (Red[d][q], pad 68)
    if (wv == 1 || wv == 3) {
        float* R = (wv == 1) ? RedA : RedB;
#pragma unroll
        for (int qg = 0; qg < 4; ++qg)
#pragma unroll
            for (int dg = 0; dg < 4; ++dg)
                *(floatx4*)&R[(dg * 16 + l15) * 68 + qg * 16 + quad * 4] = o[qg][dg];
    }
    __syncthreads();
    if (wv == 0 || wv == 2) {
        const float* R = (wv == 0) ? RedA : RedB;
#pragma unroll
        for (int qg = 0; qg < 4; ++qg)
#pragma unroll
            for (int dg = 0; dg < 4; ++dg)
                o[qg][dg] += *(const floatx4*)&R[(dg * 16 + l15) * 68 + qg * 16 + quad * 4];
    }
    __syncthreads();
    if (wv == 2) {
#pragma unroll
        for (int qg = 0; qg < 4; ++qg)
#pragma unroll
            for (int dg = 0; dg < 4; ++dg)
                *(floatx4*)&RedA[(dg * 16 + l15) * 68 + qg * 16 + quad * 4] = o[qg][dg];
    }
    __syncthreads();
    if (wv == 0) {
#pragma unroll
        for (int qg = 0; qg < 4; ++qg) {
#pragma unroll
            for (int dg = 0; dg < 4; ++dg)
                o[qg][dg] += *(const floatx4*)&RedA[(dg * 16 + l15) * 68 + qg * 16 + quad * 4];
            // total lp for queries qg*16 + quad*4 + r
            floatx4 lt = *(const floatx4*)&lpbuf[0 * 64 + qg * 16 + quad * 4];
            lt += *(const floatx4*)&lpbuf[1 * 64 + qg * 16 + quad * 4];
            lt += *(const floatx4*)&lpbuf[2 * 64 + qg * 16 + quad * 4];
            lt += *(const floatx4*)&lpbuf[3 * 64 + qg * 16 + quad * 4];
#pragma unroll
            for (int r = 0; r < 4; ++r) {
                const float inv = 1.0f / lt[r];
                const int row = qBase + qg * 16 + quad * 4 + r;
#pragma unroll
                for (int dg = 0; dg < 4; ++dg)
                    Cb[(size_t)row * D_MODEL + dg * 16 + l15] = f2bf(o[qg][dg][r] * inv);
            }
        }
    }
}

// ---------------------------------------------------------------------------
extern "C" void kernel_launch(void* const* d_in, const int* in_sizes, int n_in,
                              void* d_out, int out_size, void* d_ws, size_t ws_size,
                              hipStream_t stream) {
    const float* hs = (const float*)d_in[0];
    const float* Wq = (const float*)d_in[1];
    const float* Wk = (const float*)d_in[2];
    const float* Wv = (const float*)d_in[3];
    const float* Wo = (const float*)d_in[4];
    const float* bo = (const float*)d_in[5];
    float* out = (float*)d_out;

    const size_t NHS = (size_t)2 * S_LEN * D_MODEL;  // 4M elements
    const size_t NW  = (size_t)D_MODEL * D_MODEL;    // 1M elements

    u16* hsb = (u16*)d_ws;        // 4M
    u16* Wb  = hsb + NHS;         // 4 x 1M (Wq,Wk,Wv,Wo) — contiguous with hsb
    u16* Qb  = Wb + 4 * NW;       // 4M
    u16* Kb  = Qb + NHS;          // 4M
    u16* Vfb = Kb + NHS;          // 4M (standard projection layout)
    u16* Vtb = Vfb + NHS;         // 4M (per-head transposed [d][s])
    u16* Cxb = Vtb + NHS;         // 4M

    cast_all<<<4096, 256, 0, stream>>>(hs, Wq, Wk, Wv, Wo, hsb);

    gemm_qkv<<<768, 256, 0, stream>>>(hsb, Wb, Wb + NW, Wb + 2 * NW,
                                      Qb, Kb, Vfb);

    vtrans<<<dim3(16, 32), 256, 0, stream>>>(Vfb, Vtb);

    attn6<<<1024, 256, 0, stream>>>(Qb, Kb, Vtb, Cxb);

    gemm_out<<<dim3(8, 64), 256, 0, stream>>>(Cxb, Wb + 3 * NW, bo, out);
}